// Round 4
// baseline (121.252 us; speedup 1.0000x reference)
//
#include <hip/hip_runtime.h>

constexpr int SLN = 512, BSZ = 128, TAG = 32;
constexpr float INVLN2 = 1.4426950408889634f;
constexpr float LN2f = 0.6931471805599453f;

__device__ __forceinline__ float exp2_fast(float x) { return __builtin_amdgcn_exp2f(x); }
__device__ __forceinline__ float log2_fast(float x) { return __builtin_amdgcn_logf(x); }

// broadcast lane N of each 16-lane row to the whole row (DPP row_newbcast, VALU-only)
template<int N>
__device__ __forceinline__ float dpp_rowbcast(float v) {
  const int i = __float_as_int(v);
  return __int_as_float(__builtin_amdgcn_update_dpp(i, i, 0x150 + N, 0xF, 0xF, false));
}
__device__ __forceinline__ void pl16_swap(float& x, float& y) {
  asm("v_permlane16_swap_b32 %0, %1" : "+v"(x), "+v"(y));
}
__device__ __forceinline__ void pl32_swap(float& x, float& y) {
  asm("v_permlane32_swap_b32 %0, %1" : "+v"(x), "+v"(y));
}

struct AU { float a, u; };

// One CRF step. ucur layout: rows = [a0-15, a0-15, a16-31, a16-31].
// Lane (row r, idx i): j = i + 16*(r&1), k-half = r>>1.
// Returns a (j-layout, replicated across 32-halves) and next ucur.
__device__ __forceinline__ AU crf_step(float ucur, const float (&E)[16], float em, bool useQ) {
  const float emf = exp2_fast(em * INVLN2);
  float acc0 = 0.f, acc1 = 0.f;
#define KS(n) { const float bc = dpp_rowbcast<n>(ucur); \
                if ((n) & 1) acc1 = fmaf(bc, E[n], acc1); else acc0 = fmaf(bc, E[n], acc0); }
  KS(0) KS(1) KS(2) KS(3) KS(4) KS(5) KS(6) KS(7)
  KS(8) KS(9) KS(10) KS(11) KS(12) KS(13) KS(14) KS(15)
#undef KS
  const float p = acc0 + acc1;
  float pa = p, pb = p;
  pl32_swap(pa, pb);                 // sum(pa,pb) = lo-half + hi-half, any swap direction
  const float a = (pa + pb) * emf;   // full dot * emission, j-layout [J0,J1,J0,J1]
  float qa = a, qb = a;
  pl16_swap(qa, qb);                 // outputs {even-row-expand, odd-row-expand} (order probed)
  AU r; r.a = a; r.u = useQ ? qb : qa;
  return r;
}

// Block b < BSZ: forward scan (log-partition) for batch b -> ws[b]
// Block b >= BSZ: gold-path score for batch b-BSZ        -> ws[BSZ + b]
// __launch_bounds__(64, 1): 1 wave/EU target -> full VGPR budget. Without it the
// backend capped the kernel at 36 VGPRs and spilled E[16]+buf[16] to scratch,
// putting ~16 scratch reloads on the serial critical path (R3: 276 cy/step).
__global__ __launch_bounds__(64, 1) void crf_fwd_kernel(
    const float* __restrict__ emission, const int* __restrict__ length,
    const int* __restrict__ target, const float* __restrict__ transition,
    const float* __restrict__ start_tr, const float* __restrict__ end_tr,
    float* __restrict__ ws) {
  const int blk = blockIdx.x;
  const int lane = threadIdx.x;

  if (blk < BSZ) {
    const int b = blk;
    const int len = length[b];                    // in [2, 512]
    const int j = (lane & 15) + 16 * ((lane >> 4) & 1);  // [J0,J1,J0,J1] rows
    const int kh = lane >> 5;                     // k-half per 32-half

    // one-time probe: which pl16_swap output is the even-row expand?
    int pv = lane, qv = lane;
    asm("v_permlane16_swap_b32 %0, %1" : "+v"(pv), "+v"(qv));
    const bool probe_even = (__builtin_amdgcn_readfirstlane(pv) == 0);
    const bool useQ = probe_even ? (lane >= 32) : (lane < 32);

    // E[n] = exp(transition[16*kh + n][j]), VGPR-resident
    float E[16];
#pragma unroll
    for (int n = 0; n < 16; ++n)
      E[n] = exp2_fast(transition[(16 * kh + n) * TAG + j] * INVLN2);

    const float* emb = emission + (size_t)b * SLN * TAG + j;

    // alpha in linear base-2 domain
    float a = exp2_fast((start_tr[j] + emb[0]) * INVLN2);
    float base = 0.f;
    float ucur;
    { float qa = a, qb = a; pl16_swap(qa, qb); ucur = useQ ? qb : qa; }

    // double-buffered emission prefetch, 8 steps ahead
    float buf0[8], buf1[8];
#pragma unroll
    for (int u = 0; u < 8; ++u) buf0[u] = emb[(1 + u) * TAG];

    const int steps = len - 1;                    // >= 1
    const int nfull = steps >> 3;
    const int tail = steps & 7;

    for (int kb = 0; kb < nfull; ++kb) {
      const int t0 = 1 + (kb << 3);
#pragma unroll
      for (int u = 0; u < 8; ++u) {
        int tp = t0 + 8 + u; tp = tp < SLN ? tp : SLN - 1;
        buf1[u] = emb[tp * TAG];
      }
#pragma unroll
      for (int u = 0; u < 8; ++u) {
        const AU r = crf_step(ucur, E, buf0[u], useQ);
        a = r.a; ucur = r.u;
      }
      // exact power-of-two renorm once per 8 steps (u lane0 = a[0])
      {
        const unsigned ab = (unsigned)__builtin_amdgcn_readfirstlane(__float_as_int(ucur));
        const int e = (int)((ab >> 23) & 255u) - 127;
        const float scale = __int_as_float((127 - e) << 23);  // * 2^-e, exact
        ucur *= scale; a *= scale;
        base += (float)e;
      }
#pragma unroll
      for (int u = 0; u < 8; ++u) buf0[u] = buf1[u];
    }

    if (tail) {
#pragma unroll
      for (int u = 0; u < 7; ++u) {
        const AU r = crf_step(ucur, E, buf0[u], useQ);
        const bool take = (u < tail);             // wave-uniform
        a = take ? r.a : a;
        ucur = take ? r.u : ucur;
      }
    }

    // log_partition = ln2 * (base + log2(0.5 * sum_lanes a_j * exp(end_j)))
    float v = a * exp2_fast(end_tr[j] * INVLN2);
#pragma unroll
    for (int m = 32; m >= 1; m >>= 1) v += __shfl_xor(v, m, 64);
    if (lane == 0) ws[b] = LN2f * (base + log2_fast(0.5f * v));

  } else {
    const int b = blk - BSZ;
    const int len = length[b];
    const int* tg = target + b * SLN;
    float s = 0.f;
#pragma unroll
    for (int k0 = 0; k0 < SLN; k0 += 64) {
      const int k = k0 + lane;
      if (k < len) {
        const int tk = tg[k];
        s += emission[((size_t)b * SLN + k) * TAG + tk];
        if (k >= 1) s += transition[tg[k - 1] * TAG + tk];
      }
    }
#pragma unroll
    for (int m = 32; m >= 1; m >>= 1) s += __shfl_xor(s, m, 64);
    if (lane == 0) {
      s += start_tr[tg[0]] + end_tr[tg[len - 1]];
      ws[BSZ + b] = s;
    }
  }
}

__global__ __launch_bounds__(64) void crf_reduce_kernel(const float* __restrict__ ws,
                                                        float* __restrict__ out) {
  const int lane = threadIdx.x;
  float v = (ws[lane] - ws[BSZ + lane]) + (ws[lane + 64] - ws[BSZ + lane + 64]);
#pragma unroll
  for (int m = 32; m >= 1; m >>= 1) v += __shfl_xor(v, m, 64);
  if (lane == 0) out[0] = v;
}

extern "C" void kernel_launch(void* const* d_in, const int* in_sizes, int n_in,
                              void* d_out, int out_size, void* d_ws, size_t ws_size,
                              hipStream_t stream) {
  const float* emission   = (const float*)d_in[0];
  const int*   length     = (const int*)d_in[1];
  const int*   target     = (const int*)d_in[2];
  const float* transition = (const float*)d_in[3];
  const float* start_tr   = (const float*)d_in[4];
  const float* end_tr     = (const float*)d_in[5];
  float* ws = (float*)d_ws;   // 256 floats: [0,128) logZ, [128,256) score

  crf_fwd_kernel<<<2 * BSZ, 64, 0, stream>>>(emission, length, target, transition,
                                             start_tr, end_tr, ws);
  crf_reduce_kernel<<<1, 64, 0, stream>>>(ws, (float*)d_out);
}

// Round 5
// 119.788 us; speedup vs baseline: 1.0122x; 1.0122x over previous
//
#include <hip/hip_runtime.h>

constexpr int SLN = 512, BSZ = 128, TAG = 32;
constexpr float INVLN2 = 1.4426950408889634f;
constexpr float LN2f = 0.6931471805599453f;

__device__ __forceinline__ float exp2_fast(float x) { return __builtin_amdgcn_exp2f(x); }
__device__ __forceinline__ float log2_fast(float x) { return __builtin_amdgcn_logf(x); }

// broadcast lane N of each 16-lane row to the whole row (DPP row_newbcast, VALU-only)
template<int N>
__device__ __forceinline__ float dpp_rowbcast(float v) {
  const int i = __float_as_int(v);
  return __int_as_float(__builtin_amdgcn_update_dpp(i, i, 0x150 + N, 0xF, 0xF, false));
}
__device__ __forceinline__ void pl16_swap(float& x, float& y) {
  asm("v_permlane16_swap_b32 %0, %1" : "+v"(x), "+v"(y));
}
__device__ __forceinline__ void pl32_swap(float& x, float& y) {
  asm("v_permlane32_swap_b32 %0, %1" : "+v"(x), "+v"(y));
}
// async global->LDS, 16B per lane: lds[base + lane*16] <- g[lane addr]
__device__ __forceinline__ void gload_lds16(const float* g, float* lds_uniform) {
  __builtin_amdgcn_global_load_lds(
      (const __attribute__((address_space(1))) unsigned int*)g,
      (__attribute__((address_space(3))) unsigned int*)lds_uniform, 16, 0, 0);
}

struct AU { float a, u; };

// One CRF step. ucur layout: rows = [a0-15, a0-15, a16-31, a16-31].
// Lane (row r, idx i): j = i + 16*(r&1), k-half = r>>1.
__device__ __forceinline__ AU crf_step(float ucur, const float (&E)[16], float em, bool useQ) {
  const float emf = exp2_fast(em * INVLN2);
  float acc0 = 0.f, acc1 = 0.f;
#define KS(n) { const float bc = dpp_rowbcast<n>(ucur); \
                if ((n) & 1) acc1 = fmaf(bc, E[n], acc1); else acc0 = fmaf(bc, E[n], acc0); }
  KS(0) KS(1) KS(2) KS(3) KS(4) KS(5) KS(6) KS(7)
  KS(8) KS(9) KS(10) KS(11) KS(12) KS(13) KS(14) KS(15)
#undef KS
  const float p = acc0 + acc1;
  float pa = p, pb = p;
  pl32_swap(pa, pb);                 // sum(pa,pb) = lo-half + hi-half, any swap direction
  const float a = (pa + pb) * emf;   // full dot * emission, j-layout [J0,J1,J0,J1]
  float qa = a, qb = a;
  pl16_swap(qa, qb);                 // outputs {even-row-expand, odd-row-expand} (probed)
  AU r; r.a = a; r.u = useQ ? qb : qa;
  return r;
}

// Block b < BSZ: forward scan (log-partition) for batch b -> ws[b]
// Block b >= BSZ: gold-path score for batch b-BSZ        -> ws[BSZ + b]
__global__ __launch_bounds__(64, 1) void crf_fwd_kernel(
    const float* __restrict__ emission, const int* __restrict__ length,
    const int* __restrict__ target, const float* __restrict__ transition,
    const float* __restrict__ start_tr, const float* __restrict__ end_tr,
    float* __restrict__ ws) {
  const int blk = blockIdx.x;
  const int lane = threadIdx.x;
  __shared__ float smem[SLN * TAG];   // 64 KB: this batch's emission slice [t][j]

  if (blk < BSZ) {
    const int b = blk;

    // ---- stage emission[b] into LDS: 64 x (64 lanes x 16B) = 64 KB, fire-and-forget
    const float* gembase = emission + (size_t)b * SLN * TAG;
    {
      const float* gl = gembase + lane * 4;
#pragma unroll
      for (int i = 0; i < 64; ++i)
        gload_lds16(gl + i * 256, &smem[i * 256]);
    }

    const int len = length[b];                    // in [2, 512]
    const int j = (lane & 15) + 16 * ((lane >> 4) & 1);  // [J0,J1,J0,J1] rows
    const int kh = lane >> 5;                     // k-half per 32-half

    // one-time probe: which pl16_swap output is the even-row expand?
    int pv = lane, qv = lane;
    asm("v_permlane16_swap_b32 %0, %1" : "+v"(pv), "+v"(qv));
    const bool probe_even = (__builtin_amdgcn_readfirstlane(pv) == 0);
    const bool useQ = probe_even ? (lane >= 32) : (lane < 32);

    // E[n] = exp(transition[16*kh + n][j]), VGPR-resident (overlaps the staging)
    float E[16];
#pragma unroll
    for (int n = 0; n < 16; ++n)
      E[n] = exp2_fast(transition[(16 * kh + n) * TAG + j] * INVLN2);
    const float st = start_tr[j];

    // drain the staging before any LDS read (single wave: no barrier needed)
    asm volatile("s_waitcnt vmcnt(0)" ::: "memory");

    // alpha in linear base-2 domain
    float a = exp2_fast((st + smem[j]) * INVLN2);
    float base = 0.f;
    float ucur;
    { float qa = a, qb = a; pl16_swap(qa, qb); ucur = useQ ? qb : qa; }

    // double-buffered emission prefetch from LDS, 8 steps ahead
    float buf0[8], buf1[8];
#pragma unroll
    for (int u = 0; u < 8; ++u) buf0[u] = smem[(1 + u) * TAG + j];

    const int steps = len - 1;                    // >= 1
    const int nfull = steps >> 3;
    const int tail = steps & 7;

    for (int kb = 0; kb < nfull; ++kb) {
      const int t0 = 1 + (kb << 3);
#pragma unroll
      for (int u = 0; u < 8; ++u) {
        int tp = t0 + 8 + u; tp = tp < SLN ? tp : SLN - 1;
        buf1[u] = smem[tp * TAG + j];
      }
#pragma unroll
      for (int u = 0; u < 8; ++u) {
        const AU r = crf_step(ucur, E, buf0[u], useQ);
        a = r.a; ucur = r.u;
      }
      // exact power-of-two renorm once per 8 steps (ucur lane0 = a[0])
      {
        const unsigned ab = (unsigned)__builtin_amdgcn_readfirstlane(__float_as_int(ucur));
        const int e = (int)((ab >> 23) & 255u) - 127;
        const float scale = __int_as_float((127 - e) << 23);  // * 2^-e, exact
        ucur *= scale; a *= scale;
        base += (float)e;
      }
#pragma unroll
      for (int u = 0; u < 8; ++u) buf0[u] = buf1[u];
    }

    if (tail) {
#pragma unroll
      for (int u = 0; u < 7; ++u) {
        const AU r = crf_step(ucur, E, buf0[u], useQ);
        const bool take = (u < tail);             // wave-uniform
        a = take ? r.a : a;
        ucur = take ? r.u : ucur;
      }
    }

    // log_partition = ln2 * (base + log2(0.5 * sum_lanes a_j * exp(end_j)))
    float v = a * exp2_fast(end_tr[j] * INVLN2);
#pragma unroll
    for (int m = 32; m >= 1; m >>= 1) v += __shfl_xor(v, m, 64);
    if (lane == 0) ws[b] = LN2f * (base + log2_fast(0.5f * v));

  } else {
    const int b = blk - BSZ;
    const int len = length[b];
    const int* tg = target + b * SLN;
    float s = 0.f;
#pragma unroll
    for (int k0 = 0; k0 < SLN; k0 += 64) {
      const int k = k0 + lane;
      if (k < len) {
        const int tk = tg[k];
        s += emission[((size_t)b * SLN + k) * TAG + tk];
        if (k >= 1) s += transition[tg[k - 1] * TAG + tk];
      }
    }
#pragma unroll
    for (int m = 32; m >= 1; m >>= 1) s += __shfl_xor(s, m, 64);
    if (lane == 0) {
      s += start_tr[tg[0]] + end_tr[tg[len - 1]];
      ws[BSZ + b] = s;
    }
  }
}

__global__ __launch_bounds__(64) void crf_reduce_kernel(const float* __restrict__ ws,
                                                        float* __restrict__ out) {
  const int lane = threadIdx.x;
  float v = (ws[lane] - ws[BSZ + lane]) + (ws[lane + 64] - ws[BSZ + lane + 64]);
#pragma unroll
  for (int m = 32; m >= 1; m >>= 1) v += __shfl_xor(v, m, 64);
  if (lane == 0) out[0] = v;
}

extern "C" void kernel_launch(void* const* d_in, const int* in_sizes, int n_in,
                              void* d_out, int out_size, void* d_ws, size_t ws_size,
                              hipStream_t stream) {
  const float* emission   = (const float*)d_in[0];
  const int*   length     = (const int*)d_in[1];
  const int*   target     = (const int*)d_in[2];
  const float* transition = (const float*)d_in[3];
  const float* start_tr   = (const float*)d_in[4];
  const float* end_tr     = (const float*)d_in[5];
  float* ws = (float*)d_ws;   // 256 floats: [0,128) logZ, [128,256) score

  crf_fwd_kernel<<<2 * BSZ, 64, 0, stream>>>(emission, length, target, transition,
                                             start_tr, end_tr, ws);
  crf_reduce_kernel<<<1, 64, 0, stream>>>(ws, (float*)d_out);
}

// Round 6
// 103.828 us; speedup vs baseline: 1.1678x; 1.1537x over previous
//
#include <hip/hip_runtime.h>

constexpr int SLN = 512, BSZ = 128, TAG = 32;
constexpr float INVLN2 = 1.4426950408889634f;
constexpr float LN2f = 0.6931471805599453f;

__device__ __forceinline__ float exp2_fast(float x) { return __builtin_amdgcn_exp2f(x); }
__device__ __forceinline__ float log2_fast(float x) { return __builtin_amdgcn_logf(x); }

__device__ __forceinline__ void pl16_swap(float& x, float& y) {
  asm("v_permlane16_swap_b32 %0, %1" : "+v"(x), "+v"(y));
}
__device__ __forceinline__ void pl32_swap(float& x, float& y) {
  asm("v_permlane32_swap_b32 %0, %1" : "+v"(x), "+v"(y));
}
// async global->LDS, 16B per lane
__device__ __forceinline__ void gload_lds16(const float* g, float* lds_uniform) {
  __builtin_amdgcn_global_load_lds(
      (const __attribute__((address_space(1))) unsigned int*)g,
      (__attribute__((address_space(3))) unsigned int*)lds_uniform, 16, 0, 0);
}

// Fused broadcast-FMA matvec: p0+p1 = sum_n bcast<n>(ucur) * E[n], per 16-lane row.
// DPP row_newbcast:n broadcasts lane n of each row to the whole row; fused into
// v_mul/v_fmac (R5 showed the compiler emits separate v_mov_dpp + v_fmac: ~46
// inst/step; this block is 17). s_nop 1 covers the VALU-write -> DPP-read hazard
// on ucur (assembler does not auto-insert wait states for inline asm).
__device__ __forceinline__ void matvec16(float& p0, float& p1, float ucur, const float (&E)[16]) {
  asm("s_nop 1\n\t"
      "v_mul_f32_dpp  %0, %2, %3  row_newbcast:0  row_mask:0xf bank_mask:0xf\n\t"
      "v_mul_f32_dpp  %1, %2, %4  row_newbcast:1  row_mask:0xf bank_mask:0xf\n\t"
      "v_fmac_f32_dpp %0, %2, %5  row_newbcast:2  row_mask:0xf bank_mask:0xf\n\t"
      "v_fmac_f32_dpp %1, %2, %6  row_newbcast:3  row_mask:0xf bank_mask:0xf\n\t"
      "v_fmac_f32_dpp %0, %2, %7  row_newbcast:4  row_mask:0xf bank_mask:0xf\n\t"
      "v_fmac_f32_dpp %1, %2, %8  row_newbcast:5  row_mask:0xf bank_mask:0xf\n\t"
      "v_fmac_f32_dpp %0, %2, %9  row_newbcast:6  row_mask:0xf bank_mask:0xf\n\t"
      "v_fmac_f32_dpp %1, %2, %10 row_newbcast:7  row_mask:0xf bank_mask:0xf\n\t"
      "v_fmac_f32_dpp %0, %2, %11 row_newbcast:8  row_mask:0xf bank_mask:0xf\n\t"
      "v_fmac_f32_dpp %1, %2, %12 row_newbcast:9  row_mask:0xf bank_mask:0xf\n\t"
      "v_fmac_f32_dpp %0, %2, %13 row_newbcast:10 row_mask:0xf bank_mask:0xf\n\t"
      "v_fmac_f32_dpp %1, %2, %14 row_newbcast:11 row_mask:0xf bank_mask:0xf\n\t"
      "v_fmac_f32_dpp %0, %2, %15 row_newbcast:12 row_mask:0xf bank_mask:0xf\n\t"
      "v_fmac_f32_dpp %1, %2, %16 row_newbcast:13 row_mask:0xf bank_mask:0xf\n\t"
      "v_fmac_f32_dpp %0, %2, %17 row_newbcast:14 row_mask:0xf bank_mask:0xf\n\t"
      "v_fmac_f32_dpp %1, %2, %18 row_newbcast:15 row_mask:0xf bank_mask:0xf"
      : "=&v"(p0), "=&v"(p1)
      : "v"(ucur), "v"(E[0]), "v"(E[1]), "v"(E[2]), "v"(E[3]), "v"(E[4]),
        "v"(E[5]), "v"(E[6]), "v"(E[7]), "v"(E[8]), "v"(E[9]), "v"(E[10]),
        "v"(E[11]), "v"(E[12]), "v"(E[13]), "v"(E[14]), "v"(E[15]));
}

// Lane mapping: row r = lane>>4, i = lane&15.
//   k-half kh = r>>1  (rows 0,1: k 0-15 "A"; rows 2,3: k 16-31 "B")
//   j       = i + 16*(r&1)  -> rows [J0,J1,J0,J1]
//   ucur row r holds a[16*kh + i]  -> rows [A,A,B,B] (row_newbcast:n yields a[16*kh+n])
// One step: p (partial per kh) -> pl32_swap+add (combine k-halves; direction-proof,
// x+y = lo+hi either way) -> *emf -> pl16_swap+cndmask rebuilds [A,A,B,B].
__device__ __forceinline__ float crf_step2(float ucur, const float (&E)[16], float em, bool selx) {
  const float emf = exp2_fast(em * INVLN2);   // off the critical chain (em prefetched)
  float p0, p1;
  matvec16(p0, p1, ucur, E);
  float x = p0 + p1, y = x;
  pl32_swap(x, y);
  const float a = (x + y) * emf;   // j-layout [J0,J1,J0,J1]
  float xx = a, yy = a;
  pl16_swap(xx, yy);               // one reg = all-J0 rows, other = all-J1 (order probed)
  return selx ? xx : yy;
}

// Block b < BSZ: forward scan (log-partition) for batch b -> ws[b]
// Block b >= BSZ: gold-path score for batch b-BSZ        -> ws[BSZ + b]
__global__ __launch_bounds__(64, 1) void crf_fwd_kernel(
    const float* __restrict__ emission, const int* __restrict__ length,
    const int* __restrict__ target, const float* __restrict__ transition,
    const float* __restrict__ start_tr, const float* __restrict__ end_tr,
    float* __restrict__ ws) {
  const int blk = blockIdx.x;
  const int lane = threadIdx.x;
  __shared__ float smem[SLN * TAG];   // 64 KB: this batch's emission slice [t][j]

  if (blk < BSZ) {
    const int b = blk;

    // stage emission[b] into LDS: 64 x (64 lanes x 16B) = 64 KB, fire-and-forget
    const float* gembase = emission + (size_t)b * SLN * TAG;
    {
      const float* gl = gembase + lane * 4;
#pragma unroll
      for (int i = 0; i < 64; ++i)
        gload_lds16(gl + i * 256, &smem[i * 256]);
    }

    const int len = length[b];                       // in [2, 512]
    const int r = lane >> 4;
    const int j = (lane & 15) + 16 * (r & 1);        // rows [J0,J1,J0,J1]
    const int kh = lane >> 5;                        // k-half = r>>1

    // one-time probe of permlane16_swap output ordering
    int pv = lane, qv = lane;
    asm("v_permlane16_swap_b32 %0, %1" : "+v"(pv), "+v"(qv));
    const bool s1 = (__builtin_amdgcn_readfirstlane(pv) == 0);
    const bool selx = (lane < 32) == s1;             // lanes<32 take the all-J0 register

    // E[n] = exp(transition[16*kh + n][j]), VGPR-resident (overlaps staging)
    float E[16];
#pragma unroll
    for (int n = 0; n < 16; ++n)
      E[n] = exp2_fast(transition[(16 * kh + n) * TAG + j] * INVLN2);
    const float st = start_tr[j];

    asm volatile("s_waitcnt vmcnt(0)" ::: "memory"); // staging done (single wave)

    // alpha in linear base-2 domain; carry only ucur ([A,A,B,B] layout)
    float base = 0.f;
    float ucur;
    {
      const float a0 = exp2_fast((st + smem[j]) * INVLN2);   // j-layout
      float xx = a0, yy = a0;
      pl16_swap(xx, yy);
      ucur = selx ? xx : yy;
    }

    // double-buffered emission prefetch from LDS, 8 steps ahead
    float buf0[8], buf1[8];
#pragma unroll
    for (int u = 0; u < 8; ++u) buf0[u] = smem[(1 + u) * TAG + j];

    const int steps = len - 1;                       // >= 1
    const int nfull = steps >> 3;
    const int tail = steps & 7;

    for (int kb = 0; kb < nfull; ++kb) {
      const int t0 = 1 + (kb << 3);
#pragma unroll
      for (int u = 0; u < 8; ++u) {
        int tp = t0 + 8 + u; tp = tp < SLN ? tp : SLN - 1;
        buf1[u] = smem[tp * TAG + j];
      }
#pragma unroll
      for (int u = 0; u < 8; ++u)
        ucur = crf_step2(ucur, E, buf0[u], selx);
      // exact power-of-two renorm once per 8 steps (lane0 of ucur = a[0])
      {
        const unsigned ab = (unsigned)__builtin_amdgcn_readfirstlane(__float_as_int(ucur));
        const int e = (int)((ab >> 23) & 255u) - 127;
        ucur *= __int_as_float((127 - e) << 23);     // * 2^-e, exact
        base += (float)e;
      }
#pragma unroll
      for (int u = 0; u < 8; ++u) buf0[u] = buf1[u];
    }

    if (tail) {
#pragma unroll
      for (int u = 0; u < 7; ++u) {
        const float nu = crf_step2(ucur, E, buf0[u], selx);
        ucur = (u < tail) ? nu : ucur;               // wave-uniform mask
      }
    }

    // lane holds a[16*(lane>>5) + (lane&15)], each j appearing twice:
    // logZ = ln2 * (base + log2(sum_lanes a*exp(end)) - 1)
    const int jj = (lane & 15) + 16 * (lane >> 5);
    float v = ucur * exp2_fast(end_tr[jj] * INVLN2);
#pragma unroll
    for (int m = 32; m >= 1; m >>= 1) v += __shfl_xor(v, m, 64);
    if (lane == 0) ws[b] = LN2f * (base + log2_fast(v) - 1.0f);

  } else {
    const int b = blk - BSZ;
    const int len = length[b];
    const int* tg = target + b * SLN;
    float s = 0.f;
#pragma unroll
    for (int k0 = 0; k0 < SLN; k0 += 64) {
      const int k = k0 + lane;
      if (k < len) {
        const int tk = tg[k];
        s += emission[((size_t)b * SLN + k) * TAG + tk];
        if (k >= 1) s += transition[tg[k - 1] * TAG + tk];
      }
    }
#pragma unroll
    for (int m = 32; m >= 1; m >>= 1) s += __shfl_xor(s, m, 64);
    if (lane == 0) {
      s += start_tr[tg[0]] + end_tr[tg[len - 1]];
      ws[BSZ + b] = s;
    }
  }
}

__global__ __launch_bounds__(64) void crf_reduce_kernel(const float* __restrict__ ws,
                                                        float* __restrict__ out) {
  const int lane = threadIdx.x;
  float v = (ws[lane] - ws[BSZ + lane]) + (ws[lane + 64] - ws[BSZ + lane + 64]);
#pragma unroll
  for (int m = 32; m >= 1; m >>= 1) v += __shfl_xor(v, m, 64);
  if (lane == 0) out[0] = v;
}

extern "C" void kernel_launch(void* const* d_in, const int* in_sizes, int n_in,
                              void* d_out, int out_size, void* d_ws, size_t ws_size,
                              hipStream_t stream) {
  const float* emission   = (const float*)d_in[0];
  const int*   length     = (const int*)d_in[1];
  const int*   target     = (const int*)d_in[2];
  const float* transition = (const float*)d_in[3];
  const float* start_tr   = (const float*)d_in[4];
  const float* end_tr     = (const float*)d_in[5];
  float* ws = (float*)d_ws;   // 256 floats: [0,128) logZ, [128,256) score

  crf_fwd_kernel<<<2 * BSZ, 64, 0, stream>>>(emission, length, target, transition,
                                             start_tr, end_tr, ws);
  crf_reduce_kernel<<<1, 64, 0, stream>>>(ws, (float*)d_out);
}